// Round 22
// baseline (100.062 us; speedup 1.0000x reference)
//
#include <hip/hip_runtime.h>
#include <hip/hip_bf16.h>
#include <math.h>

// Problem constants: B=16, H=W=128, C=64, M1=M2=16
// Workspace layout (float offsets):
#define OFF_TBL 0u            // 128 x {cos,sin}(2*pi*m/128)          (256)
#define OFF_S1  256u          // instance-norm-1 raw sums [b*64+c][2] (2048)
#define OFF_S2  2304u         // instance-norm-2 stats (s1,s2)        (2048)
#define OFF_PQ  4352u         // PT2[b][hp32][ky16][c64][ri2][h4] u32 bf16 hi|lo (4194304)
                              //   aliased later with Q[b][h][ky][o][2] f32
#define OFF_X   4198656u      // X[b][kx][ky][c][2] f32               (1048576)
#define OFF_O   5247232u      // Out[b][kx][ky][o][2] f32             (1048576)
                              //   head doubles (pre-mix) as u16 trig tables:
                              //   FdAh[32][128] @0, FdAl @4096, EdAh[64][128] @8192, EdAl @16384
#define OFF_WT  6295808u      // WT[mode][i][o][2]                    (4194304)
// total = 10490112 floats = 41.96 MB
// X region is dead after k_mix -> reuse as u16 arrays for bf16-split MLP weights:
//   u16[0..8192) w1hi   [8192..16384) w1lo   [16384..24576) w2hi
//   [24576..32768) w2lo  [32768..36864) Mhi  [36864..40960) Mlo

typedef __attribute__((ext_vector_type(8))) short bfrag;
typedef __attribute__((ext_vector_type(4))) float f4v;
#define MFMA(A,B,C) __builtin_amdgcn_mfma_f32_16x16x32_bf16(A,B,C,0,0,0)

// compile-time float4 component select -- NO address-taken indexing (scratch hazard)
#define F4GET(v, i) ((i)==0 ? (v).x : (i)==1 ? (v).y : (i)==2 ? (v).z : (v).w)

__device__ __forceinline__ unsigned short f2bf_rn(float x) {
    unsigned u = __float_as_uint(x);
    unsigned r = u + 0x7FFFu + ((u >> 16) & 1u);
    return (unsigned short)(r >> 16);
}
// native RNE conversion (same rounding as f2bf_rn; compiler emits v_cvt)
__device__ __forceinline__ unsigned short f2bf_n(float x) {
    __hip_bfloat16 b = __float2bfloat16(x);
    return __builtin_bit_cast(unsigned short, b);
}
__device__ __forceinline__ float bf2f(unsigned short h) {
    return __uint_as_float(((unsigned)h) << 16);
}
__device__ __forceinline__ void split2(float x, unsigned short& hi, unsigned short& lo) {
    hi = f2bf_rn(x);
    lo = f2bf_rn(x - bf2f(hi));
}
// GELU, sigmoid-rcp form: 0.5x(1+tanh(u)) == x * rcp(1 + exp(-2u)),
// u = 0.79788456(x + 0.044715 x^3). Matches exact GELU <1e-5 for |x|<=0.5.
__device__ __forceinline__ float gelu_t(float x) {
    float t2 = x*x*x;
    float p = __builtin_fmaf(0.044715f, t2, x);
    float e = __expf(-1.5957691216057308f * p);
    return x * __builtin_amdgcn_rcpf(1.f + e);
}

// async DMA: 64 lanes x 16B -> LDS at (uniform base + lane*16)
__device__ __forceinline__ void gload_lds16(const float* g, float* l) {
    __builtin_amdgcn_global_load_lds(
        (const __attribute__((address_space(1))) void*)g,
        (__attribute__((address_space(3))) void*)l, 16, 0, 0);
}

// block 0: twiddle table + zero S1/S2. blocks 1..48: bf16-split trig tables
// (F for dftw, E for dfth) into the O region (dead until k_mix overwrites).
__global__ void k_init(float* __restrict__ ws) {
    int t = threadIdx.x, bid = blockIdx.x;
    if (bid == 0) {
        if (t < 128) {
            double ang = 6.283185307179586476925286766559 * (double)t / 128.0;
            ws[OFF_TBL + 2*t]     = (float)cos(ang);
            ws[OFF_TBL + 2*t + 1] = (float)sin(ang);
        }
        for (int i = t; i < 4096; i += 256) ws[OFF_S1 + i] = 0.f;
        return;
    }
    int e = (bid - 1)*256 + t;   // 0..12287
    unsigned short* OU = (unsigned short*)(ws + OFF_O);
    const double TWO_PI = 6.283185307179586476925286766559;
    if (e < 4096) {              // FdA[row=ri*16+ky][w]: re rows cos, im rows -sin
        int row = e >> 7, w = e & 127, ky = row & 15;
        double ang = TWO_PI * (double)((ky * w) & 127) / 128.0;
        double v = (row < 16) ? cos(ang) : -sin(ang);
        unsigned short hi, lo; split2((float)v, hi, lo);
        OU[e] = hi; OU[4096 + e] = lo;
    } else {                     // EdA[row=2kx+s][h]: s=0 cos, s=1 sin (of freq f(kx))
        int e2 = e - 4096, row = e2 >> 7, h = e2 & 127;
        int kx = row >> 1, f = kx < 16 ? kx : 96 + kx;
        double ang = TWO_PI * (double)((f * h) & 127) / 128.0;
        double v = (row & 1) ? sin(ang) : cos(ang);
        unsigned short hi, lo; split2((float)v, hi, lo);
        OU[8192 + e2] = hi; OU[16384 + e2] = lo;
    }
}

// MERGED: blocks [0,512) = MFMA forward DFT-w via DOUBLE-BUFFERED
// global_load_lds DMA (counted vmcnt(8) -- never drained mid-loop; A-frags
// preloaded so vmcnt counts are pure); blocks [512,640) = weight transpose.
__global__ __launch_bounds__(256) void k_big(const float* __restrict__ x,
        const float* __restrict__ w1r, const float* __restrict__ w1i,
        const float* __restrict__ w2r, const float* __restrict__ w2i,
        float* __restrict__ ws) {
    __shared__ __align__(16) char smem[66560];
    int bid = blockIdx.x;
    int t = threadIdx.x;
    if (bid < 512) {
        // ================= dftw branch (pipelined DMA ingest) =================
        float* Xf = (float*)smem;     // per-wave 2 x [8 calls][260 f32]
        int hp = bid & 31, b = bid >> 5;
        int l = t & 63, wv = t >> 6;
        const unsigned short* OU = (const unsigned short*)(ws + OFF_O);
        const unsigned short* FdAh = OU, *FdAl = OU + 4096;
        f4v acc[2][4];
        #pragma unroll
        for (int mt = 0; mt < 2; mt++)
            #pragma unroll
            for (int nt = 0; nt < 4; nt++) acc[mt][nt] = (f4v){0.f,0.f,0.f,0.f};
        float s1a[4] = {0,0,0,0}, s2a[4] = {0,0,0,0};   // per nt: c = nt*16 + (l&15)
        const float* xb = x + ((long)(b*128 + hp*4 + wv))*8192;   // this wave's h row
        float* buf0 = Xf + wv*4160;
        float* buf1 = buf0 + 2080;

        // ---- preload ALL A-frags (16 global loads; drained by first vmcnt(8)) ----
        bfrag mah[4][2], mal[4][2];
        #pragma unroll
        for (int kc = 0; kc < 4; kc++) {
            int kglob = kc*32 + (l >> 4)*8;
            #pragma unroll
            for (int mt = 0; mt < 2; mt++) {
                int row = mt*16 + (l & 15);
                mah[kc][mt] = *(const bfrag*)(FdAh + row*128 + kglob);
                mal[kc][mt] = *(const bfrag*)(FdAl + row*128 + kglob);
            }
        }
        #define DFTW_ISSUE(KC, BUF)                                           \
            _Pragma("unroll")                                                 \
            for (int j = 0; j < 8; j++)                                       \
                gload_lds16(xb + ((KC)*32 + j*4)*64 + l*4, (BUF) + j*260);
        #define DFTW_COMPUTE(KC, BUF)                                         \
            _Pragma("unroll")                                                 \
            for (int nt = 0; nt < 4; nt++) {                                  \
                bfrag bh;                                                     \
                _Pragma("unroll")                                             \
                for (int j = 0; j < 8; j++) {                                 \
                    int k = (l >> 4)*8 + j;                                   \
                    float f = (BUF)[(k >> 2)*260 + (k & 3)*64 + nt*16 + (l & 15)]; \
                    s1a[nt] += f;                                             \
                    s2a[nt] += f*f;                                           \
                    bh[j] = (short)f2bf_rn(f);                                \
                }                                                             \
                _Pragma("unroll")                                             \
                for (int mt = 0; mt < 2; mt++) {                              \
                    f4v a_ = acc[mt][nt];                                     \
                    a_ = MFMA(mah[KC][mt], bh, a_);                           \
                    a_ = MFMA(mal[KC][mt], bh, a_);                           \
                    acc[mt][nt] = a_;                                         \
                }                                                             \
            }

        DFTW_ISSUE(0, buf0);
        DFTW_ISSUE(1, buf1);
        asm volatile("s_waitcnt vmcnt(8)" ::: "memory");   // A-frags + c0 done; c1 in flight
        __builtin_amdgcn_sched_barrier(0);
        DFTW_COMPUTE(0, buf0);
        asm volatile("s_waitcnt lgkmcnt(0)" ::: "memory"); // buf0 reads drained
        __builtin_amdgcn_sched_barrier(0);
        DFTW_ISSUE(2, buf0);
        asm volatile("s_waitcnt vmcnt(8)" ::: "memory");   // c1 done; c2 in flight
        __builtin_amdgcn_sched_barrier(0);
        DFTW_COMPUTE(1, buf1);
        asm volatile("s_waitcnt lgkmcnt(0)" ::: "memory"); // buf1 reads drained
        __builtin_amdgcn_sched_barrier(0);
        DFTW_ISSUE(3, buf1);
        asm volatile("s_waitcnt vmcnt(8)" ::: "memory");   // c2 done; c3 in flight
        __builtin_amdgcn_sched_barrier(0);
        DFTW_COMPUTE(2, buf0);
        asm volatile("s_waitcnt vmcnt(0)" ::: "memory");   // c3 done
        __builtin_amdgcn_sched_barrier(0);
        DFTW_COMPUTE(3, buf1);
        #undef DFTW_ISSUE
        #undef DFTW_COMPUTE

        // ---- stats reduce (quads share c) + atomics ----
        #pragma unroll
        for (int nt = 0; nt < 4; nt++) {
            s1a[nt] += __shfl_down(s1a[nt], 16, 64);
            s1a[nt] += __shfl_down(s1a[nt], 32, 64);
            s2a[nt] += __shfl_down(s2a[nt], 16, 64);
            s2a[nt] += __shfl_down(s2a[nt], 32, 64);
        }
        if (l < 16) {
            #pragma unroll
            for (int nt = 0; nt < 4; nt++) {
                int c = nt*16 + l;
                atomicAdd(&ws[OFF_S1 + (b*64 + c)*2],     s1a[nt]);
                atomicAdd(&ws[OFF_S1 + (b*64 + c)*2 + 1], s2a[nt]);
            }
        }
        // ---- epilogue: pack -> TB (aliases Xf), then block-contiguous PT2 ----
        __syncthreads();
        unsigned* TB = (unsigned*)smem;   // TB[ky][c*2+ri][h4], stride 520 u32/ky
        #pragma unroll
        for (int mt = 0; mt < 2; mt++)
            #pragma unroll
            for (int nt = 0; nt < 4; nt++)
                #pragma unroll
                for (int rr = 0; rr < 4; rr++) {
                    float v = acc[mt][nt][rr];
                    unsigned short hi, lo; split2(v, hi, lo);
                    int trow = mt*16 + (l >> 4)*4 + rr;
                    int ri = trow >> 4, ky = trow & 15;
                    int c = nt*16 + (l & 15);
                    TB[ky*520 + (c*2 + ri)*4 + wv] = ((unsigned)hi << 16) | lo;
                }
        __syncthreads();
        unsigned* PTb = (unsigned*)(ws + OFF_PQ) + ((long)(b*32 + hp))*8192;
        #pragma unroll
        for (int i = 0; i < 8; i++) {
            int idx = i*256 + t;
            int ky = idx >> 7, m = idx & 127;
            ((uint4*)PTb)[idx] = *(const uint4*)(TB + ky*520 + m*4);
        }
    } else {
        // ================= trans branch =================
        float* Lr = (float*)smem;           // [16][257]
        float* Li = Lr + 16*257;
        int rel = bid - 512;
        int i = rel & 63, part = rel >> 6;
        float* WT = ws + OFF_WT;
        const float* wr = part ? w2r : w1r;
        const float* wi = part ? w2i : w1i;
        for (int oc = 0; oc < 4; oc++) {
            int o0 = oc * 16;
            __syncthreads();
            for (int idx = t; idx < 4096; idx += 256) {
                int oo = idx >> 8, m = idx & 255;
                Lr[oo*257 + m] = wr[(i*64 + o0 + oo)*256 + m];
                Li[oo*257 + m] = wi[(i*64 + o0 + oo)*256 + m];
            }
            __syncthreads();
            for (int idx = t; idx < 8192; idx += 256) {
                int mode = idx >> 5, rem = idx & 31, oo = rem >> 1, ri = rem & 1;
                float val = ri ? Li[oo*257 + mode] : Lr[oo*257 + mode];
                int gm = part*256 + mode;
                WT[((gm*64 + i)*64 + (o0 + oo))*2 + ri] = val;
            }
        }
    }
}

// MFMA forward DFT along h: X[2kx+s][(c,ri)] = EdA @ PT2 (per ky,b).
// Staging reads 2KB contiguous runs per (hp,ky). grid (ky=16, b=16).
__global__ __launch_bounds__(256) void k_dfth(float* __restrict__ ws) {
    __shared__ unsigned Bsh[16384];   // BTh 32KB (128 cols x 256B) | BTl 32KB
    int t = threadIdx.x;
    int ky = blockIdx.x, b = blockIdx.y;
    int l = t & 63, wv = t >> 6;
    char* bh_base = (char*)Bsh;
    char* bl_base = bh_base + 32768;
    const uint4* PT4 = (const uint4*)((const unsigned*)(ws + OFF_PQ));
    const unsigned short* OU = (const unsigned short*)(ws + OFF_O);
    const unsigned short* EdAh = OU + 8192, *EdAl = OU + 16384;

    #pragma unroll
    for (int i = 0; i < 16; i++) {
        int idx = i*256 + t;
        int hp = idx >> 7, n = idx & 127;
        uint4 v = PT4[((long)(b*32 + hp)*16 + ky)*128 + n];
        unsigned h01 = (v.x >> 16) | (v.y & 0xFFFF0000u);
        unsigned h23 = (v.z >> 16) | (v.w & 0xFFFF0000u);
        unsigned l01 = (v.x & 0xFFFFu) | (v.y << 16);
        unsigned l23 = (v.z & 0xFFFFu) | (v.w << 16);
        int kk = hp*4;
        unsigned ad = (unsigned)(n*256 + ((kk*2) ^ ((n & 7) << 4)));
        *(uint2*)(bh_base + ad) = make_uint2(h01, h23);
        *(uint2*)(bl_base + ad) = make_uint2(l01, l23);
    }
    bfrag ea_h[4], ea_l[4];
    #pragma unroll
    for (int kc = 0; kc < 4; kc++) {
        int off = (wv*16 + (l & 15))*128 + kc*32 + (l >> 4)*8;
        ea_h[kc] = *(const bfrag*)(EdAh + off);
        ea_l[kc] = *(const bfrag*)(EdAl + off);
    }
    __syncthreads();
    f4v acc[8];
    #pragma unroll
    for (int nt = 0; nt < 8; nt++) acc[nt] = (f4v){0.f,0.f,0.f,0.f};
    #pragma unroll
    for (int kc = 0; kc < 4; kc++)
        #pragma unroll
        for (int nt = 0; nt < 8; nt++) {
            int col = nt*16 + (l & 15);
            unsigned ro = (unsigned)(col*256 + ((kc*64 + (l >> 4)*16) ^ ((col & 7) << 4)));
            bfrag bh = *(const bfrag*)(bh_base + ro);
            bfrag bl = *(const bfrag*)(bl_base + ro);
            acc[nt] = MFMA(ea_h[kc], bh, acc[nt]);
            acc[nt] = MFMA(ea_h[kc], bl, acc[nt]);
            acc[nt] = MFMA(ea_l[kc], bh, acc[nt]);
        }
    float* X = ws + OFF_X;
    #pragma unroll
    for (int nt = 0; nt < 8; nt++)
        #pragma unroll
        for (int p = 0; p < 2; p++) {
            float s0 = acc[nt][2*p], s1 = acc[nt][2*p + 1];
            float partner = __shfl_xor(s1, 1, 64);
            float res = (l & 1) ? (s0 - partner) : (s0 + partner);
            int kx = wv*8 + (l >> 4)*2 + p;
            X[(((long)b*32 + kx)*16 + ky)*128 + nt*16 + (l & 15)] = res;
        }
}

// per-mode complex mix with rho1 scaling folded into X staging. grid 512 (=mode)
__global__ void k_mix(float* __restrict__ ws) {
    __shared__ float Wsh[8192];
    __shared__ float Xs[2048];
    __shared__ float rhoT[1024];
    int t = threadIdx.x;
    int mode = blockIdx.x;
    int kxI = mode >> 4, ky = mode & 15;
    const float* WT = ws + OFF_WT;
    const float* X = ws + OFF_X;
    float* O = ws + OFF_O;
    for (int i = t; i < 1024; i += 256) {
        float a = ws[OFF_S1 + 2*i], s = ws[OFF_S1 + 2*i + 1];
        float m = a * (1.f/16384.f);
        float v = s * (1.f/16384.f) - m*m;
        rhoT[i] = rsqrtf(v + 1e-5f);
    }
    for (int idx = t; idx < 8192; idx += 256) Wsh[idx] = WT[(long)mode*8192 + idx];
    __syncthreads();
    for (int idx = t; idx < 2048; idx += 256) {
        int b = idx >> 7, r = idx & 127;
        Xs[idx] = X[((b*32 + kxI)*16 + ky)*128 + r] * rhoT[b*64 + (r >> 1)];
    }
    __syncthreads();
    int o = t & 63, bg = t >> 6;
    float accr[4] = {0,0,0,0}, acci[4] = {0,0,0,0};
    for (int i = 0; i < 64; i++) {
        float wr = Wsh[(i*64 + o)*2], wi = Wsh[(i*64 + o)*2 + 1];
        #pragma unroll
        for (int j = 0; j < 4; j++) {
            float xr = Xs[(bg*4 + j)*128 + 2*i], xi = Xs[(bg*4 + j)*128 + 2*i + 1];
            accr[j] += xr*wr - xi*wi;
            acci[j] += xr*wi + xi*wr;
        }
    }
    #pragma unroll
    for (int j = 0; j < 4; j++) {
        int b = bg*4 + j;
        float2* dst = (float2*)(O + ((b*32 + kxI)*16 + ky)*128);
        dst[o] = make_float2(accr[j], acci[j]);
    }
}

// MERGED TAIL: blocks [0,256) = MFMA inverse DFT-h with Parseval stats folded
// into the staging pass; blocks [256,336) = MLP-weight bf16-split prep.
__global__ __launch_bounds__(256) void k_tail(const float* __restrict__ mw1,
        const float* __restrict__ mw2, float* __restrict__ ws) {
    __shared__ unsigned short BstH[128*70];   // [n=o*2+ri][k 64 pad70], swz k^8(n&7)
    __shared__ unsigned short BstL[128*70];
    __shared__ float tblL[256];
    __shared__ float redP[4][32][2];
    int bid = blockIdx.x, t = threadIdx.x;
    if (bid >= 256) {
        // ---- wmlp branch ----
        int i = (bid - 256)*256 + t;   // [0, 20480)
        unsigned short* xu = (unsigned short*)(ws + OFF_X);
        if (i < 8192) {
            unsigned short hi, lo; split2(mw1[i], hi, lo);
            xu[i] = hi; xu[8192 + i] = lo;
        } else if (i < 16384) {
            int k = i - 8192;
            unsigned short hi, lo; split2(mw2[k], hi, lo);
            xu[16384 + k] = hi; xu[24576 + k] = lo;
        } else if (i < 20480) {
            int m = i - 16384;           // w*32 + k
            int w = m >> 5, k = m & 31;
            int ky = k >> 1;
            double ang = 6.283185307179586476925286766559 * (double)((ky * w) & 127) / 128.0;
            double v = (k & 1) ? -sin(ang) : cos(ang);
            double a = (ky == 0) ? 1.0 : 2.0;
            float val = (float)(v * a) * (1.f/16384.f);
            unsigned short hi, lo; split2(val, hi, lo);
            xu[32768 + m] = hi; xu[36864 + m] = lo;
        }
        return;
    }
    // ---- idfth branch (+ pstats fold) ----
    int ky = bid & 15, b = bid >> 4;
    int l = t & 63, wv = t >> 6;
    for (int i = t; i < 256; i += 256) tblL[i] = ws[OFF_TBL + i];
    const float4* O4 = (const float4*)(ws + OFF_O);

    float pw0 = 0.f, pw1 = 0.f;
    #pragma unroll
    for (int i = 0; i < 4; i++) {
        int idx = i*256 + t;
        int kx = idx >> 5, u = idx & 31;    // u: uint4 within the 128-float row
        float4 v = O4[((long)(b*32 + kx)*16 + ky)*32 + u];
        pw0 += v.x*v.x + v.y*v.y;           // power for o = 2u
        pw1 += v.z*v.z + v.w*v.w;           // power for o = 2u+1
        int k0 = kx*2;
        #pragma unroll
        for (int p = 0; p < 2; p++) {
            float orr = p ? v.z : v.x;
            float oii = p ? v.w : v.y;
            int n0 = (u*2 + p)*2;           // re column
            int n1 = n0 + 1;                // im column
            unsigned short hi, lo;
            split2(orr, hi, lo);
            { unsigned ad = (unsigned)(n0*70 + (k0 ^ (8*(n0 & 7)))); BstH[ad]=hi; BstL[ad]=lo; }
            { unsigned ad = (unsigned)(n1*70 + ((k0+1) ^ (8*(n1 & 7)))); BstH[ad]=hi; BstL[ad]=lo; }
            split2(oii, hi, lo);
            { unsigned ad = (unsigned)(n1*70 + (k0 ^ (8*(n1 & 7)))); BstH[ad]=hi; BstL[ad]=lo; }
            split2(-oii, hi, lo);
            { unsigned ad = (unsigned)(n0*70 + ((k0+1) ^ (8*(n0 & 7)))); BstH[ad]=hi; BstL[ad]=lo; }
        }
    }
    pw0 += __shfl_down(pw0, 32, 64);
    pw1 += __shfl_down(pw1, 32, 64);
    if (l < 32) { redP[wv][l][0] = pw0; redP[wv][l][1] = pw1; }
    __syncthreads();
    if (t < 64) {
        int u = t >> 1, oo = t & 1;
        int o = t;
        float p = redP[0][u][oo] + redP[1][u][oo] + redP[2][u][oo] + redP[3][u][oo];
        float s2add = (ky == 0 ? 0.5f : 2.f) * p;
        if (ky == 0) {
            const float* Ob = ws + OFF_O + (long)b*65536;
            float ar0 = Ob[2*o], ai0 = Ob[2*o + 1];
            float t1 = ar0*ar0 - ai0*ai0;
            for (int k = 1; k <= 15; k++) {
                float xr = Ob[(k*16)*128 + 2*o],        xi = Ob[(k*16)*128 + 2*o + 1];
                float yr = Ob[((32-k)*16)*128 + 2*o],   yi = Ob[((32-k)*16)*128 + 2*o + 1];
                t1 += 2.f*(xr*yr - xi*yi);
            }
            s2add += 0.5f*t1;
            ws[OFF_S2 + (b*64 + o)*2] = ar0;    // s1 (mean term), unique writer
        }
        atomicAdd(&ws[OFF_S2 + (b*64 + o)*2 + 1], s2add * (1.f/16384.f));
    }
    bfrag ah_[2][2], al_[2][2];
    #pragma unroll
    for (int q = 0; q < 2; q++) {
        int h = (wv*2 + q)*16 + (l & 15);
        #pragma unroll
        for (int kcl = 0; kcl < 2; kcl++) {
            int kbase = kcl*32 + (l >> 4)*8;
            bfrag vh, vl;
            #pragma unroll
            for (int j = 0; j < 8; j++) {
                int k = kbase + j;
                int kx = k >> 1, f = kx < 16 ? kx : 96 + kx;
                int m = (f * h) & 127;
                float val = (k & 1) ? tblL[2*m + 1] : tblL[2*m];
                unsigned short hi, lo; split2(val, hi, lo);
                vh[j] = (short)hi; vl[j] = (short)lo;
            }
            ah_[q][kcl] = vh; al_[q][kcl] = vl;
        }
    }
    f4v acc[2][8];
    #pragma unroll
    for (int q = 0; q < 2; q++)
        #pragma unroll
        for (int nt = 0; nt < 8; nt++) acc[q][nt] = (f4v){0.f,0.f,0.f,0.f};
    #pragma unroll
    for (int kcl = 0; kcl < 2; kcl++)
        #pragma unroll
        for (int nt = 0; nt < 8; nt++) {
            int n = nt*16 + (l & 15);
            unsigned ku = (unsigned)((kcl*32 + (l >> 4)*8) ^ (8*(n & 7)));
            bfrag bh = *(const bfrag*)(BstH + n*70 + ku);
            bfrag bl = *(const bfrag*)(BstL + n*70 + ku);
            #pragma unroll
            for (int q = 0; q < 2; q++) {
                f4v a_ = acc[q][nt];
                a_ = MFMA(ah_[q][kcl], bh, a_);
                a_ = MFMA(ah_[q][kcl], bl, a_);
                a_ = MFMA(al_[q][kcl], bh, a_);
                acc[q][nt] = a_;
            }
        }
    float* Q = ws + OFF_PQ;
    #pragma unroll
    for (int q = 0; q < 2; q++)
        #pragma unroll
        for (int nt = 0; nt < 8; nt++)
            #pragma unroll
            for (int r = 0; r < 4; r++) {
                int h = (wv*2 + q)*16 + (l >> 4)*4 + r;
                Q[((long)(b*128 + h))*2048 + ky*128 + nt*16 + (l & 15)] = acc[q][nt][r];
            }
}

// fused MFMA kernel: Y = M@Qm (iDFT-w), z = (Y-mu)*rho, h = GELU(z@W1+b1),
// out = h@W2+b2. VALU diet: native bf16 cvts + sigmoid-rcp GELU.
// 52.5KB LDS -> 3 blocks/CU. grid (h=128,b=16).
__global__ __launch_bounds__(256, 3) void k_mlp(const float* __restrict__ mb1,
                      const float* __restrict__ mb2,
                      float* __restrict__ out, const float* __restrict__ ws) {
    __shared__ unsigned short zhS[8192];        // z[w][64c] swz (w&7)<<4; ALIASED as h-half after za read
    __shared__ unsigned short w1hS[8192];       // w1[j][64c], swz (j&7)<<4
    __shared__ unsigned short w2hS[8192];       // w2[o][128j], swz (o&15)<<4
    __shared__ unsigned short qhS[2304];        // QmT[c][36k] single-bf16 (k=2ky+ri, 32 used)
    int t = threadIdx.x;
    int h = blockIdx.x, b = blockIdx.y;
    int l = t & 63, wv = t >> 6;

    const unsigned short* xu = (const unsigned short*)(ws + OFF_X);
    const unsigned short* w1hG = xu;
    const unsigned short* w2hG = xu + 16384;
    const unsigned short* MhG  = xu + 32768, *MlG  = xu + 36864;

    for (int ch = t; ch < 1024; ch += 256) {       // w1: rows j, stride 128B
        int j = ch >> 3, c0 = (ch & 7) * 8;
        unsigned off = (unsigned)(j*128 + c0*2) ^ (unsigned)((j & 7) << 4);
        *(bfrag*)((char*)w1hS + off) = *(const bfrag*)(w1hG + ch*8);
    }
    for (int ch = t; ch < 1024; ch += 256) {       // w2: rows o, stride 256B
        int o = ch >> 4, j0 = (ch & 15) * 8;
        unsigned off = (unsigned)(o*256 + j0*2) ^ (unsigned)((o & 15) << 4);
        *(bfrag*)((char*)w2hS + off) = *(const bfrag*)(w2hG + ch*8);
    }
    // ---- Q staging: coalesced (c fast), single-bf16, native cvt ----
    const float* Qp = ws + OFF_PQ + (long)(b*128 + h)*2048;
    for (int i = t; i < 2048; i += 256) {
        int c = i & 63, k = i >> 6;
        float v = Qp[(k >> 1)*128 + c*2 + (k & 1)];
        qhS[c*36 + k] = f2bf_n(v);
    }
    bfrag ma_h[2], ma_l[2];
    #pragma unroll
    for (int q = 0; q < 2; q++) {
        int w = (wv + 4*q)*16 + (l & 15);
        ma_h[q] = *(const bfrag*)(MhG + w*32 + (l >> 4)*8);
        ma_l[q] = *(const bfrag*)(MlG + w*32 + (l >> 4)*8);
    }
    float muA[4], rhA[4];
    #pragma unroll
    for (int ct = 0; ct < 4; ct++) {
        int c = ct*16 + (l & 15);
        float s1 = ws[OFF_S2 + (b*64 + c)*2], s2 = ws[OFF_S2 + (b*64 + c)*2 + 1];
        float m = s1 * (1.f/16384.f);
        float v = s2 * (1.f/16384.f) - m*m;
        muA[ct] = m; rhA[ct] = rsqrtf(v + 1e-5f);
    }
    __syncthreads();   // cross-wave staging -- the ONLY barrier needed

    #pragma unroll
    for (int q = 0; q < 2; q++) {
        int wt = wv + 4*q;
        #pragma unroll
        for (int ct = 0; ct < 4; ct++) {
            unsigned ro = (unsigned)((ct*16 + (l & 15))*72 + (l >> 4)*16);
            bfrag bh = *(const bfrag*)((const char*)qhS + ro);
            f4v acc = {0.f, 0.f, 0.f, 0.f};
            acc = MFMA(ma_h[q], bh, acc);
            acc = MFMA(ma_l[q], bh, acc);
            float mu_ = muA[ct], rh_ = rhA[ct];
            int c = ct*16 + (l & 15);
            #pragma unroll
            for (int r = 0; r < 4; r++) {
                int w = wt*16 + (l >> 4)*4 + r;
                float z = (acc[r] - mu_) * rh_;
                unsigned off = (unsigned)(w*128 + c*2) ^ (unsigned)((w & 7) << 4);
                *(unsigned short*)((char*)zhS + off) = f2bf_n(z);
            }
        }
    }
    bfrag za[2][2];
    #pragma unroll
    for (int q = 0; q < 2; q++) {
        int w = (wv + 4*q)*16 + (l & 15);
        #pragma unroll
        for (int ks = 0; ks < 2; ks++) {
            unsigned off = (unsigned)(w*128 + (ks*32 + (l >> 4)*8)*2) ^ (unsigned)((w & 7) << 4);
            za[q][ks] = *(const bfrag*)((const char*)zhS + off);
        }
    }
    f4v accO[2][4];
    #pragma unroll
    for (int q = 0; q < 2; q++)
        #pragma unroll
        for (int ot = 0; ot < 4; ot++) accO[q][ot] = (f4v){0.f,0.f,0.f,0.f};

    unsigned short* hhS = zhS;   // alias: both hold only this wave's 32 rows
    #pragma unroll
    for (int jh = 0; jh < 2; jh++) {
        #pragma unroll
        for (int q = 0; q < 2; q++) {
            int wt = wv + 4*q;
            #pragma unroll
            for (int jt = 0; jt < 4; jt++) {
                int j = jh*64 + jt*16 + (l & 15);
                f4v acc = {0.f, 0.f, 0.f, 0.f};
                #pragma unroll
                for (int ks = 0; ks < 2; ks++) {
                    unsigned off = (unsigned)(j*128 + (ks*32 + (l >> 4)*8)*2) ^ (unsigned)((j & 7) << 4);
                    bfrag bh = *(const bfrag*)((const char*)w1hS + off);
                    acc = MFMA(za[q][ks], bh, acc);
                }
                float bj = mb1[j];
                #pragma unroll
                for (int r = 0; r < 4; r++) {
                    int w = wt*16 + (l >> 4)*4 + r;
                    float hv = gelu_t(acc[r] + bj);
                    int jl = jt*16 + (l & 15);
                    unsigned off = (unsigned)(w*128 + jl*2) ^ (unsigned)((w & 7) << 4);
                    *(unsigned short*)((char*)hhS + off) = f2bf_n(hv);
                }
            }
        }
        #pragma unroll
        for (int q = 0; q < 2; q++) {
            int w = (wv + 4*q)*16 + (l & 15);
            bfrag ha[2];
            #pragma unroll
            for (int ks = 0; ks < 2; ks++) {
                unsigned off = (unsigned)(w*128 + (ks*32 + (l >> 4)*8)*2) ^ (unsigned)((w & 7) << 4);
                ha[ks] = *(const bfrag*)((const char*)hhS + off);
            }
            #pragma unroll
            for (int ot = 0; ot < 4; ot++) {
                int o = ot*16 + (l & 15);
                f4v acc = accO[q][ot];
                #pragma unroll
                for (int ks = 0; ks < 2; ks++) {
                    int jj = jh*64 + ks*32 + (l >> 4)*8;
                    unsigned off = (unsigned)(o*256 + jj*2) ^ (unsigned)((o & 15) << 4);
                    bfrag bh = *(const bfrag*)((const char*)w2hS + off);
                    acc = MFMA(ha[ks], bh, acc);
                }
                accO[q][ot] = acc;
            }
        }
    }
    #pragma unroll
    for (int q = 0; q < 2; q++) {
        int wt = wv + 4*q;
        #pragma unroll
        for (int ot = 0; ot < 4; ot++) {
            int o = ot*16 + (l & 15);
            float bo = mb2[o];
            #pragma unroll
            for (int r = 0; r < 4; r++) {
                int w = wt*16 + (l >> 4)*4 + r;
                out[((long)(b*128 + h)*128 + w)*64 + o] = accO[q][ot][r] + bo;
            }
        }
    }
}

extern "C" void kernel_launch(void* const* d_in, const int* in_sizes, int n_in,
                              void* d_out, int out_size, void* d_ws, size_t ws_size,
                              hipStream_t stream) {
    const float* x   = (const float*)d_in[0];
    const float* w1r = (const float*)d_in[1];
    const float* w1i = (const float*)d_in[2];
    const float* w2r = (const float*)d_in[3];
    const float* w2i = (const float*)d_in[4];
    const float* mw1 = (const float*)d_in[5];
    const float* mb1 = (const float*)d_in[6];
    const float* mw2 = (const float*)d_in[7];
    const float* mb2 = (const float*)d_in[8];
    float* ws  = (float*)d_ws;
    float* out = (float*)d_out;

    k_init <<<dim3(49),      dim3(256), 0, stream>>>(ws);
    k_big  <<<dim3(640),     dim3(256), 0, stream>>>(x, w1r, w1i, w2r, w2i, ws); // dftw(dbuf DMA) ∪ trans
    k_dfth <<<dim3(16,16),   dim3(256), 0, stream>>>(ws);
    k_mix  <<<dim3(512),     dim3(256), 0, stream>>>(ws);
    k_tail <<<dim3(336),     dim3(256), 0, stream>>>(mw1, mw2, ws);  // idfth+pstats ∪ wmlp
    k_mlp  <<<dim3(128,16),  dim3(256), 0, stream>>>(mb1, mb2, out, ws);
}

// Round 23
// 97.154 us; speedup vs baseline: 1.0299x; 1.0299x over previous
//
#include <hip/hip_runtime.h>
#include <hip/hip_bf16.h>
#include <math.h>

// Problem constants: B=16, H=W=128, C=64, M1=M2=16
// Workspace layout (float offsets):
#define OFF_TBL 0u            // 128 x {cos,sin}(2*pi*m/128)          (256)
#define OFF_S1  256u          // instance-norm-1 raw sums [b*64+c][2] (2048)
#define OFF_S2  2304u         // instance-norm-2 stats (s1,s2)        (2048)
#define OFF_PQ  4352u         // PT2[b][hp32][ky16][c64][ri2][h4] u32 bf16 hi|lo (4194304)
                              //   aliased later with Q[b][h][ky][o][2] f32
#define OFF_X   4198656u      // X[b][kx][ky][c][2] f32               (1048576)
#define OFF_O   5247232u      // Out[b][kx][ky][o][2] f32             (1048576)
                              //   head doubles (pre-mix) as u16 trig tables:
                              //   FdAh[32][128] @0, FdAl @4096, EdAh[64][128] @8192, EdAl @16384
#define OFF_WT  6295808u      // WT[mode][i][o][2]                    (4194304)
// total = 10490112 floats = 41.96 MB
// X region is dead after k_mix -> reuse as u16 arrays for bf16-split MLP weights:
//   u16[0..8192) w1hi   [8192..16384) w1lo   [16384..24576) w2hi
//   [24576..32768) w2lo  [32768..36864) Mhi  [36864..40960) Mlo

typedef __attribute__((ext_vector_type(8))) short bfrag;
typedef __attribute__((ext_vector_type(4))) float f4v;
#define MFMA(A,B,C) __builtin_amdgcn_mfma_f32_16x16x32_bf16(A,B,C,0,0,0)

// compile-time float4 component select -- NO address-taken indexing (scratch hazard)
#define F4GET(v, i) ((i)==0 ? (v).x : (i)==1 ? (v).y : (i)==2 ? (v).z : (v).w)

__device__ __forceinline__ unsigned short f2bf_rn(float x) {
    unsigned u = __float_as_uint(x);
    unsigned r = u + 0x7FFFu + ((u >> 16) & 1u);
    return (unsigned short)(r >> 16);
}
// native RNE conversion (same rounding as f2bf_rn; compiler emits v_cvt)
__device__ __forceinline__ unsigned short f2bf_n(float x) {
    __hip_bfloat16 b = __float2bfloat16(x);
    return __builtin_bit_cast(unsigned short, b);
}
__device__ __forceinline__ float bf2f(unsigned short h) {
    return __uint_as_float(((unsigned)h) << 16);
}
__device__ __forceinline__ void split2(float x, unsigned short& hi, unsigned short& lo) {
    hi = f2bf_rn(x);
    lo = f2bf_rn(x - bf2f(hi));
}
// GELU, sigmoid-rcp form: 0.5x(1+tanh(u)) == x * rcp(1 + exp(-2u)),
// u = 0.79788456(x + 0.044715 x^3). Matches exact GELU <1e-5 for |x|<=0.5.
__device__ __forceinline__ float gelu_t(float x) {
    float t2 = x*x*x;
    float p = __builtin_fmaf(0.044715f, t2, x);
    float e = __expf(-1.5957691216057308f * p);
    return x * __builtin_amdgcn_rcpf(1.f + e);
}

// async DMA: 64 lanes x 16B -> LDS at (uniform base + lane*16)
__device__ __forceinline__ void gload_lds16(const float* g, float* l) {
    __builtin_amdgcn_global_load_lds(
        (const __attribute__((address_space(1))) void*)g,
        (__attribute__((address_space(3))) void*)l, 16, 0, 0);
}

// block 0: twiddle table + zero S1/S2. blocks 1..48: bf16-split trig tables
// (F for dftw, E for dfth) into the O region (dead until k_mix overwrites).
__global__ void k_init(float* __restrict__ ws) {
    int t = threadIdx.x, bid = blockIdx.x;
    if (bid == 0) {
        if (t < 128) {
            double ang = 6.283185307179586476925286766559 * (double)t / 128.0;
            ws[OFF_TBL + 2*t]     = (float)cos(ang);
            ws[OFF_TBL + 2*t + 1] = (float)sin(ang);
        }
        for (int i = t; i < 4096; i += 256) ws[OFF_S1 + i] = 0.f;
        return;
    }
    int e = (bid - 1)*256 + t;   // 0..12287
    unsigned short* OU = (unsigned short*)(ws + OFF_O);
    const double TWO_PI = 6.283185307179586476925286766559;
    if (e < 4096) {              // FdA[row=ri*16+ky][w]: re rows cos, im rows -sin
        int row = e >> 7, w = e & 127, ky = row & 15;
        double ang = TWO_PI * (double)((ky * w) & 127) / 128.0;
        double v = (row < 16) ? cos(ang) : -sin(ang);
        unsigned short hi, lo; split2((float)v, hi, lo);
        OU[e] = hi; OU[4096 + e] = lo;
    } else {                     // EdA[row=2kx+s][h]: s=0 cos, s=1 sin (of freq f(kx))
        int e2 = e - 4096, row = e2 >> 7, h = e2 & 127;
        int kx = row >> 1, f = kx < 16 ? kx : 96 + kx;
        double ang = TWO_PI * (double)((f * h) & 127) / 128.0;
        double v = (row & 1) ? sin(ang) : cos(ang);
        unsigned short hi, lo; split2((float)v, hi, lo);
        OU[8192 + e2] = hi; OU[16384 + e2] = lo;
    }
}

// MERGED: blocks [0,512) = MFMA forward DFT-w via global_load_lds DMA (f32 x
// straight to LDS, convert at frag-build, stats folded there; wave-private
// chunks -> no block barriers in K-loop); blocks [512,640) = weight transpose.
// (R21 serial-DMA version -- the R22 double-buffer variant regressed.)
__global__ __launch_bounds__(256) void k_big(const float* __restrict__ x,
        const float* __restrict__ w1r, const float* __restrict__ w1i,
        const float* __restrict__ w2r, const float* __restrict__ w2i,
        float* __restrict__ ws) {
    __shared__ __align__(16) char smem[33280];
    int bid = blockIdx.x;
    int t = threadIdx.x;
    if (bid < 512) {
        // ================= dftw branch (DMA ingest) =================
        float* Xf = (float*)smem;     // per-wave [8 calls][260 f32] (1040B calls, pad 16B)
        int hp = bid & 31, b = bid >> 5;
        int l = t & 63, wv = t >> 6;
        const unsigned short* OU = (const unsigned short*)(ws + OFF_O);
        const unsigned short* FdAh = OU, *FdAl = OU + 4096;
        f4v acc[2][4];
        #pragma unroll
        for (int mt = 0; mt < 2; mt++)
            #pragma unroll
            for (int nt = 0; nt < 4; nt++) acc[mt][nt] = (f4v){0.f,0.f,0.f,0.f};
        float s1a[4] = {0,0,0,0}, s2a[4] = {0,0,0,0};   // per nt: c = nt*16 + (l&15)
        const float* xb = x + ((long)(b*128 + hp*4 + wv))*8192;   // this wave's h row
        float* XfW = Xf + wv*2080;

        for (int kc = 0; kc < 4; kc++) {
            if (kc) {   // prior chunk's ds_reads must complete before DMA overwrite
                asm volatile("s_waitcnt lgkmcnt(0)" ::: "memory");
                __builtin_amdgcn_sched_barrier(0);
            }
            #pragma unroll
            for (int j = 0; j < 8; j++)
                gload_lds16(xb + (kc*32 + j*4)*64 + l*4, XfW + j*260);
            // A-frags for this chunk (global, L2-hot); covered by the vmcnt wait
            int kglob = kc*32 + (l >> 4)*8;
            bfrag mah[2], mal[2];
            #pragma unroll
            for (int mt = 0; mt < 2; mt++) {
                int row = mt*16 + (l & 15);
                mah[mt] = *(const bfrag*)(FdAh + row*128 + kglob);
                mal[mt] = *(const bfrag*)(FdAl + row*128 + kglob);
            }
            asm volatile("s_waitcnt vmcnt(0)" ::: "memory");
            __builtin_amdgcn_sched_barrier(0);
            #pragma unroll
            for (int nt = 0; nt < 4; nt++) {
                bfrag bh;
                #pragma unroll
                for (int j = 0; j < 8; j++) {
                    int k = (l >> 4)*8 + j;
                    float f = XfW[(k >> 2)*260 + (k & 3)*64 + nt*16 + (l & 15)];
                    s1a[nt] += f;
                    s2a[nt] += f*f;
                    bh[j] = (short)f2bf_rn(f);
                }
                #pragma unroll
                for (int mt = 0; mt < 2; mt++) {
                    f4v a_ = acc[mt][nt];
                    a_ = MFMA(mah[mt], bh, a_);
                    a_ = MFMA(mal[mt], bh, a_);
                    acc[mt][nt] = a_;
                }
            }
        }
        // ---- stats reduce (quads share c) + atomics ----
        #pragma unroll
        for (int nt = 0; nt < 4; nt++) {
            s1a[nt] += __shfl_down(s1a[nt], 16, 64);
            s1a[nt] += __shfl_down(s1a[nt], 32, 64);
            s2a[nt] += __shfl_down(s2a[nt], 16, 64);
            s2a[nt] += __shfl_down(s2a[nt], 32, 64);
        }
        if (l < 16) {
            #pragma unroll
            for (int nt = 0; nt < 4; nt++) {
                int c = nt*16 + l;
                atomicAdd(&ws[OFF_S1 + (b*64 + c)*2],     s1a[nt]);
                atomicAdd(&ws[OFF_S1 + (b*64 + c)*2 + 1], s2a[nt]);
            }
        }
        // ---- epilogue: pack -> TB (aliases Xf), then block-contiguous PT2 ----
        __syncthreads();
        unsigned* TB = (unsigned*)smem;   // TB[ky][c*2+ri][h4], stride 520 u32/ky
        #pragma unroll
        for (int mt = 0; mt < 2; mt++)
            #pragma unroll
            for (int nt = 0; nt < 4; nt++)
                #pragma unroll
                for (int rr = 0; rr < 4; rr++) {
                    float v = acc[mt][nt][rr];
                    unsigned short hi, lo; split2(v, hi, lo);
                    int trow = mt*16 + (l >> 4)*4 + rr;
                    int ri = trow >> 4, ky = trow & 15;
                    int c = nt*16 + (l & 15);
                    TB[ky*520 + (c*2 + ri)*4 + wv] = ((unsigned)hi << 16) | lo;
                }
        __syncthreads();
        unsigned* PTb = (unsigned*)(ws + OFF_PQ) + ((long)(b*32 + hp))*8192;
        #pragma unroll
        for (int i = 0; i < 8; i++) {
            int idx = i*256 + t;
            int ky = idx >> 7, m = idx & 127;
            ((uint4*)PTb)[idx] = *(const uint4*)(TB + ky*520 + m*4);
        }
    } else {
        // ================= trans branch =================
        float* Lr = (float*)smem;           // [16][257]
        float* Li = Lr + 16*257;
        int rel = bid - 512;
        int i = rel & 63, part = rel >> 6;
        float* WT = ws + OFF_WT;
        const float* wr = part ? w2r : w1r;
        const float* wi = part ? w2i : w1i;
        for (int oc = 0; oc < 4; oc++) {
            int o0 = oc * 16;
            __syncthreads();
            for (int idx = t; idx < 4096; idx += 256) {
                int oo = idx >> 8, m = idx & 255;
                Lr[oo*257 + m] = wr[(i*64 + o0 + oo)*256 + m];
                Li[oo*257 + m] = wi[(i*64 + o0 + oo)*256 + m];
            }
            __syncthreads();
            for (int idx = t; idx < 8192; idx += 256) {
                int mode = idx >> 5, rem = idx & 31, oo = rem >> 1, ri = rem & 1;
                float val = ri ? Li[oo*257 + mode] : Lr[oo*257 + mode];
                int gm = part*256 + mode;
                WT[((gm*64 + i)*64 + (o0 + oo))*2 + ri] = val;
            }
        }
    }
}

// MFMA forward DFT along h: X[2kx+s][(c,ri)] = EdA @ PT2 (per ky,b).
// Staging reads 2KB contiguous runs per (hp,ky). grid (ky=16, b=16).
__global__ __launch_bounds__(256) void k_dfth(float* __restrict__ ws) {
    __shared__ unsigned Bsh[16384];   // BTh 32KB (128 cols x 256B) | BTl 32KB
    int t = threadIdx.x;
    int ky = blockIdx.x, b = blockIdx.y;
    int l = t & 63, wv = t >> 6;
    char* bh_base = (char*)Bsh;
    char* bl_base = bh_base + 32768;
    const uint4* PT4 = (const uint4*)((const unsigned*)(ws + OFF_PQ));
    const unsigned short* OU = (const unsigned short*)(ws + OFF_O);
    const unsigned short* EdAh = OU + 8192, *EdAl = OU + 16384;

    #pragma unroll
    for (int i = 0; i < 16; i++) {
        int idx = i*256 + t;
        int hp = idx >> 7, n = idx & 127;
        uint4 v = PT4[((long)(b*32 + hp)*16 + ky)*128 + n];
        unsigned h01 = (v.x >> 16) | (v.y & 0xFFFF0000u);
        unsigned h23 = (v.z >> 16) | (v.w & 0xFFFF0000u);
        unsigned l01 = (v.x & 0xFFFFu) | (v.y << 16);
        unsigned l23 = (v.z & 0xFFFFu) | (v.w << 16);
        int kk = hp*4;
        unsigned ad = (unsigned)(n*256 + ((kk*2) ^ ((n & 7) << 4)));
        *(uint2*)(bh_base + ad) = make_uint2(h01, h23);
        *(uint2*)(bl_base + ad) = make_uint2(l01, l23);
    }
    bfrag ea_h[4], ea_l[4];
    #pragma unroll
    for (int kc = 0; kc < 4; kc++) {
        int off = (wv*16 + (l & 15))*128 + kc*32 + (l >> 4)*8;
        ea_h[kc] = *(const bfrag*)(EdAh + off);
        ea_l[kc] = *(const bfrag*)(EdAl + off);
    }
    __syncthreads();
    f4v acc[8];
    #pragma unroll
    for (int nt = 0; nt < 8; nt++) acc[nt] = (f4v){0.f,0.f,0.f,0.f};
    #pragma unroll
    for (int kc = 0; kc < 4; kc++)
        #pragma unroll
        for (int nt = 0; nt < 8; nt++) {
            int col = nt*16 + (l & 15);
            unsigned ro = (unsigned)(col*256 + ((kc*64 + (l >> 4)*16) ^ ((col & 7) << 4)));
            bfrag bh = *(const bfrag*)(bh_base + ro);
            bfrag bl = *(const bfrag*)(bl_base + ro);
            acc[nt] = MFMA(ea_h[kc], bh, acc[nt]);
            acc[nt] = MFMA(ea_h[kc], bl, acc[nt]);
            acc[nt] = MFMA(ea_l[kc], bh, acc[nt]);
        }
    float* X = ws + OFF_X;
    #pragma unroll
    for (int nt = 0; nt < 8; nt++)
        #pragma unroll
        for (int p = 0; p < 2; p++) {
            float s0 = acc[nt][2*p], s1 = acc[nt][2*p + 1];
            float partner = __shfl_xor(s1, 1, 64);
            float res = (l & 1) ? (s0 - partner) : (s0 + partner);
            int kx = wv*8 + (l >> 4)*2 + p;
            X[(((long)b*32 + kx)*16 + ky)*128 + nt*16 + (l & 15)] = res;
        }
}

// per-mode complex mix with rho1 scaling folded into X staging. grid 512 (=mode)
__global__ void k_mix(float* __restrict__ ws) {
    __shared__ float Wsh[8192];
    __shared__ float Xs[2048];
    __shared__ float rhoT[1024];
    int t = threadIdx.x;
    int mode = blockIdx.x;
    int kxI = mode >> 4, ky = mode & 15;
    const float* WT = ws + OFF_WT;
    const float* X = ws + OFF_X;
    float* O = ws + OFF_O;
    for (int i = t; i < 1024; i += 256) {
        float a = ws[OFF_S1 + 2*i], s = ws[OFF_S1 + 2*i + 1];
        float m = a * (1.f/16384.f);
        float v = s * (1.f/16384.f) - m*m;
        rhoT[i] = rsqrtf(v + 1e-5f);
    }
    for (int idx = t; idx < 8192; idx += 256) Wsh[idx] = WT[(long)mode*8192 + idx];
    __syncthreads();
    for (int idx = t; idx < 2048; idx += 256) {
        int b = idx >> 7, r = idx & 127;
        Xs[idx] = X[((b*32 + kxI)*16 + ky)*128 + r] * rhoT[b*64 + (r >> 1)];
    }
    __syncthreads();
    int o = t & 63, bg = t >> 6;
    float accr[4] = {0,0,0,0}, acci[4] = {0,0,0,0};
    for (int i = 0; i < 64; i++) {
        float wr = Wsh[(i*64 + o)*2], wi = Wsh[(i*64 + o)*2 + 1];
        #pragma unroll
        for (int j = 0; j < 4; j++) {
            float xr = Xs[(bg*4 + j)*128 + 2*i], xi = Xs[(bg*4 + j)*128 + 2*i + 1];
            accr[j] += xr*wr - xi*wi;
            acci[j] += xr*wi + xi*wr;
        }
    }
    #pragma unroll
    for (int j = 0; j < 4; j++) {
        int b = bg*4 + j;
        float2* dst = (float2*)(O + ((b*32 + kxI)*16 + ky)*128);
        dst[o] = make_float2(accr[j], acci[j]);
    }
}

// MERGED TAIL: blocks [0,256) = MFMA inverse DFT-h with Parseval stats folded
// into the staging pass; blocks [256,336) = MLP-weight bf16-split prep.
__global__ __launch_bounds__(256) void k_tail(const float* __restrict__ mw1,
        const float* __restrict__ mw2, float* __restrict__ ws) {
    __shared__ unsigned short BstH[128*70];   // [n=o*2+ri][k 64 pad70], swz k^8(n&7)
    __shared__ unsigned short BstL[128*70];
    __shared__ float tblL[256];
    __shared__ float redP[4][32][2];
    int bid = blockIdx.x, t = threadIdx.x;
    if (bid >= 256) {
        // ---- wmlp branch ----
        int i = (bid - 256)*256 + t;   // [0, 20480)
        unsigned short* xu = (unsigned short*)(ws + OFF_X);
        if (i < 8192) {
            unsigned short hi, lo; split2(mw1[i], hi, lo);
            xu[i] = hi; xu[8192 + i] = lo;
        } else if (i < 16384) {
            int k = i - 8192;
            unsigned short hi, lo; split2(mw2[k], hi, lo);
            xu[16384 + k] = hi; xu[24576 + k] = lo;
        } else if (i < 20480) {
            int m = i - 16384;           // w*32 + k
            int w = m >> 5, k = m & 31;
            int ky = k >> 1;
            double ang = 6.283185307179586476925286766559 * (double)((ky * w) & 127) / 128.0;
            double v = (k & 1) ? -sin(ang) : cos(ang);
            double a = (ky == 0) ? 1.0 : 2.0;
            float val = (float)(v * a) * (1.f/16384.f);
            unsigned short hi, lo; split2(val, hi, lo);
            xu[32768 + m] = hi; xu[36864 + m] = lo;
        }
        return;
    }
    // ---- idfth branch (+ pstats fold) ----
    int ky = bid & 15, b = bid >> 4;
    int l = t & 63, wv = t >> 6;
    for (int i = t; i < 256; i += 256) tblL[i] = ws[OFF_TBL + i];
    const float4* O4 = (const float4*)(ws + OFF_O);

    float pw0 = 0.f, pw1 = 0.f;
    #pragma unroll
    for (int i = 0; i < 4; i++) {
        int idx = i*256 + t;
        int kx = idx >> 5, u = idx & 31;    // u: uint4 within the 128-float row
        float4 v = O4[((long)(b*32 + kx)*16 + ky)*32 + u];
        pw0 += v.x*v.x + v.y*v.y;           // power for o = 2u
        pw1 += v.z*v.z + v.w*v.w;           // power for o = 2u+1
        int k0 = kx*2;
        #pragma unroll
        for (int p = 0; p < 2; p++) {
            float orr = p ? v.z : v.x;
            float oii = p ? v.w : v.y;
            int n0 = (u*2 + p)*2;           // re column
            int n1 = n0 + 1;                // im column
            unsigned short hi, lo;
            split2(orr, hi, lo);
            { unsigned ad = (unsigned)(n0*70 + (k0 ^ (8*(n0 & 7)))); BstH[ad]=hi; BstL[ad]=lo; }
            { unsigned ad = (unsigned)(n1*70 + ((k0+1) ^ (8*(n1 & 7)))); BstH[ad]=hi; BstL[ad]=lo; }
            split2(oii, hi, lo);
            { unsigned ad = (unsigned)(n1*70 + (k0 ^ (8*(n1 & 7)))); BstH[ad]=hi; BstL[ad]=lo; }
            split2(-oii, hi, lo);
            { unsigned ad = (unsigned)(n0*70 + ((k0+1) ^ (8*(n0 & 7)))); BstH[ad]=hi; BstL[ad]=lo; }
        }
    }
    pw0 += __shfl_down(pw0, 32, 64);
    pw1 += __shfl_down(pw1, 32, 64);
    if (l < 32) { redP[wv][l][0] = pw0; redP[wv][l][1] = pw1; }
    __syncthreads();
    if (t < 64) {
        int u = t >> 1, oo = t & 1;
        int o = t;
        float p = redP[0][u][oo] + redP[1][u][oo] + redP[2][u][oo] + redP[3][u][oo];
        float s2add = (ky == 0 ? 0.5f : 2.f) * p;
        if (ky == 0) {
            const float* Ob = ws + OFF_O + (long)b*65536;
            float ar0 = Ob[2*o], ai0 = Ob[2*o + 1];
            float t1 = ar0*ar0 - ai0*ai0;
            for (int k = 1; k <= 15; k++) {
                float xr = Ob[(k*16)*128 + 2*o],        xi = Ob[(k*16)*128 + 2*o + 1];
                float yr = Ob[((32-k)*16)*128 + 2*o],   yi = Ob[((32-k)*16)*128 + 2*o + 1];
                t1 += 2.f*(xr*yr - xi*yi);
            }
            s2add += 0.5f*t1;
            ws[OFF_S2 + (b*64 + o)*2] = ar0;    // s1 (mean term), unique writer
        }
        atomicAdd(&ws[OFF_S2 + (b*64 + o)*2 + 1], s2add * (1.f/16384.f));
    }
    bfrag ah_[2][2], al_[2][2];
    #pragma unroll
    for (int q = 0; q < 2; q++) {
        int h = (wv*2 + q)*16 + (l & 15);
        #pragma unroll
        for (int kcl = 0; kcl < 2; kcl++) {
            int kbase = kcl*32 + (l >> 4)*8;
            bfrag vh, vl;
            #pragma unroll
            for (int j = 0; j < 8; j++) {
                int k = kbase + j;
                int kx = k >> 1, f = kx < 16 ? kx : 96 + kx;
                int m = (f * h) & 127;
                float val = (k & 1) ? tblL[2*m + 1] : tblL[2*m];
                unsigned short hi, lo; split2(val, hi, lo);
                vh[j] = (short)hi; vl[j] = (short)lo;
            }
            ah_[q][kcl] = vh; al_[q][kcl] = vl;
        }
    }
    f4v acc[2][8];
    #pragma unroll
    for (int q = 0; q < 2; q++)
        #pragma unroll
        for (int nt = 0; nt < 8; nt++) acc[q][nt] = (f4v){0.f,0.f,0.f,0.f};
    #pragma unroll
    for (int kcl = 0; kcl < 2; kcl++)
        #pragma unroll
        for (int nt = 0; nt < 8; nt++) {
            int n = nt*16 + (l & 15);
            unsigned ku = (unsigned)((kcl*32 + (l >> 4)*8) ^ (8*(n & 7)));
            bfrag bh = *(const bfrag*)(BstH + n*70 + ku);
            bfrag bl = *(const bfrag*)(BstL + n*70 + ku);
            #pragma unroll
            for (int q = 0; q < 2; q++) {
                f4v a_ = acc[q][nt];
                a_ = MFMA(ah_[q][kcl], bh, a_);
                a_ = MFMA(ah_[q][kcl], bl, a_);
                a_ = MFMA(al_[q][kcl], bh, a_);
                acc[q][nt] = a_;
            }
        }
    float* Q = ws + OFF_PQ;
    #pragma unroll
    for (int q = 0; q < 2; q++)
        #pragma unroll
        for (int nt = 0; nt < 8; nt++)
            #pragma unroll
            for (int r = 0; r < 4; r++) {
                int h = (wv*2 + q)*16 + (l >> 4)*4 + r;
                Q[((long)(b*128 + h))*2048 + ky*128 + nt*16 + (l & 15)] = acc[q][nt][r];
            }
}

// fused MFMA kernel: Y = M@Qm (iDFT-w), z = (Y-mu)*rho, h = GELU(z@W1+b1),
// out = h@W2+b2. VALU diet: native bf16 cvts + sigmoid-rcp GELU.
// 52.5KB LDS -> 3 blocks/CU. grid (h=128,b=16).
__global__ __launch_bounds__(256, 3) void k_mlp(const float* __restrict__ mb1,
                      const float* __restrict__ mb2,
                      float* __restrict__ out, const float* __restrict__ ws) {
    __shared__ unsigned short zhS[8192];        // z[w][64c] swz (w&7)<<4; ALIASED as h-half after za read
    __shared__ unsigned short w1hS[8192];       // w1[j][64c], swz (j&7)<<4
    __shared__ unsigned short w2hS[8192];       // w2[o][128j], swz (o&15)<<4
    __shared__ unsigned short qhS[2304];        // QmT[c][36k] single-bf16 (k=2ky+ri, 32 used)
    int t = threadIdx.x;
    int h = blockIdx.x, b = blockIdx.y;
    int l = t & 63, wv = t >> 6;

    const unsigned short* xu = (const unsigned short*)(ws + OFF_X);
    const unsigned short* w1hG = xu;
    const unsigned short* w2hG = xu + 16384;
    const unsigned short* MhG  = xu + 32768, *MlG  = xu + 36864;

    for (int ch = t; ch < 1024; ch += 256) {       // w1: rows j, stride 128B
        int j = ch >> 3, c0 = (ch & 7) * 8;
        unsigned off = (unsigned)(j*128 + c0*2) ^ (unsigned)((j & 7) << 4);
        *(bfrag*)((char*)w1hS + off) = *(const bfrag*)(w1hG + ch*8);
    }
    for (int ch = t; ch < 1024; ch += 256) {       // w2: rows o, stride 256B
        int o = ch >> 4, j0 = (ch & 15) * 8;
        unsigned off = (unsigned)(o*256 + j0*2) ^ (unsigned)((o & 15) << 4);
        *(bfrag*)((char*)w2hS + off) = *(const bfrag*)(w2hG + ch*8);
    }
    // ---- Q staging: coalesced (c fast), single-bf16, native cvt ----
    const float* Qp = ws + OFF_PQ + (long)(b*128 + h)*2048;
    for (int i = t; i < 2048; i += 256) {
        int c = i & 63, k = i >> 6;
        float v = Qp[(k >> 1)*128 + c*2 + (k & 1)];
        qhS[c*36 + k] = f2bf_n(v);
    }
    bfrag ma_h[2], ma_l[2];
    #pragma unroll
    for (int q = 0; q < 2; q++) {
        int w = (wv + 4*q)*16 + (l & 15);
        ma_h[q] = *(const bfrag*)(MhG + w*32 + (l >> 4)*8);
        ma_l[q] = *(const bfrag*)(MlG + w*32 + (l >> 4)*8);
    }
    float muA[4], rhA[4];
    #pragma unroll
    for (int ct = 0; ct < 4; ct++) {
        int c = ct*16 + (l & 15);
        float s1 = ws[OFF_S2 + (b*64 + c)*2], s2 = ws[OFF_S2 + (b*64 + c)*2 + 1];
        float m = s1 * (1.f/16384.f);
        float v = s2 * (1.f/16384.f) - m*m;
        muA[ct] = m; rhA[ct] = rsqrtf(v + 1e-5f);
    }
    __syncthreads();   // cross-wave staging -- the ONLY barrier needed

    #pragma unroll
    for (int q = 0; q < 2; q++) {
        int wt = wv + 4*q;
        #pragma unroll
        for (int ct = 0; ct < 4; ct++) {
            unsigned ro = (unsigned)((ct*16 + (l & 15))*72 + (l >> 4)*16);
            bfrag bh = *(const bfrag*)((const char*)qhS + ro);
            f4v acc = {0.f, 0.f, 0.f, 0.f};
            acc = MFMA(ma_h[q], bh, acc);
            acc = MFMA(ma_l[q], bh, acc);
            float mu_ = muA[ct], rh_ = rhA[ct];
            int c = ct*16 + (l & 15);
            #pragma unroll
            for (int r = 0; r < 4; r++) {
                int w = wt*16 + (l >> 4)*4 + r;
                float z = (acc[r] - mu_) * rh_;
                unsigned off = (unsigned)(w*128 + c*2) ^ (unsigned)((w & 7) << 4);
                *(unsigned short*)((char*)zhS + off) = f2bf_n(z);
            }
        }
    }
    bfrag za[2][2];
    #pragma unroll
    for (int q = 0; q < 2; q++) {
        int w = (wv + 4*q)*16 + (l & 15);
        #pragma unroll
        for (int ks = 0; ks < 2; ks++) {
            unsigned off = (unsigned)(w*128 + (ks*32 + (l >> 4)*8)*2) ^ (unsigned)((w & 7) << 4);
            za[q][ks] = *(const bfrag*)((const char*)zhS + off);
        }
    }
    f4v accO[2][4];
    #pragma unroll
    for (int q = 0; q < 2; q++)
        #pragma unroll
        for (int ot = 0; ot < 4; ot++) accO[q][ot] = (f4v){0.f,0.f,0.f,0.f};

    unsigned short* hhS = zhS;   // alias: both hold only this wave's 32 rows
    #pragma unroll
    for (int jh = 0; jh < 2; jh++) {
        #pragma unroll
        for (int q = 0; q < 2; q++) {
            int wt = wv + 4*q;
            #pragma unroll
            for (int jt = 0; jt < 4; jt++) {
                int j = jh*64 + jt*16 + (l & 15);
                f4v acc = {0.f, 0.f, 0.f, 0.f};
                #pragma unroll
                for (int ks = 0; ks < 2; ks++) {
                    unsigned off = (unsigned)(j*128 + (ks*32 + (l >> 4)*8)*2) ^ (unsigned)((j & 7) << 4);
                    bfrag bh = *(const bfrag*)((const char*)w1hS + off);
                    acc = MFMA(za[q][ks], bh, acc);
                }
                float bj = mb1[j];
                #pragma unroll
                for (int r = 0; r < 4; r++) {
                    int w = wt*16 + (l >> 4)*4 + r;
                    float hv = gelu_t(acc[r] + bj);
                    int jl = jt*16 + (l & 15);
                    unsigned off = (unsigned)(w*128 + jl*2) ^ (unsigned)((w & 7) << 4);
                    *(unsigned short*)((char*)hhS + off) = f2bf_n(hv);
                }
            }
        }
        #pragma unroll
        for (int q = 0; q < 2; q++) {
            int w = (wv + 4*q)*16 + (l & 15);
            bfrag ha[2];
            #pragma unroll
            for (int ks = 0; ks < 2; ks++) {
                unsigned off = (unsigned)(w*128 + (ks*32 + (l >> 4)*8)*2) ^ (unsigned)((w & 7) << 4);
                ha[ks] = *(const bfrag*)((const char*)hhS + off);
            }
            #pragma unroll
            for (int ot = 0; ot < 4; ot++) {
                int o = ot*16 + (l & 15);
                f4v acc = accO[q][ot];
                #pragma unroll
                for (int ks = 0; ks < 2; ks++) {
                    int jj = jh*64 + ks*32 + (l >> 4)*8;
                    unsigned off = (unsigned)(o*256 + jj*2) ^ (unsigned)((o & 15) << 4);
                    bfrag bh = *(const bfrag*)((const char*)w2hS + off);
                    acc = MFMA(ha[ks], bh, acc);
                }
                accO[q][ot] = acc;
            }
        }
    }
    #pragma unroll
    for (int q = 0; q < 2; q++) {
        int wt = wv + 4*q;
        #pragma unroll
        for (int ot = 0; ot < 4; ot++) {
            int o = ot*16 + (l & 15);
            float bo = mb2[o];
            #pragma unroll
            for (int r = 0; r < 4; r++) {
                int w = wt*16 + (l >> 4)*4 + r;
                out[((long)(b*128 + h)*128 + w)*64 + o] = accO[q][ot][r] + bo;
            }
        }
    }
}

extern "C" void kernel_launch(void* const* d_in, const int* in_sizes, int n_in,
                              void* d_out, int out_size, void* d_ws, size_t ws_size,
                              hipStream_t stream) {
    const float* x   = (const float*)d_in[0];
    const float* w1r = (const float*)d_in[1];
    const float* w1i = (const float*)d_in[2];
    const float* w2r = (const float*)d_in[3];
    const float* w2i = (const float*)d_in[4];
    const float* mw1 = (const float*)d_in[5];
    const float* mb1 = (const float*)d_in[6];
    const float* mw2 = (const float*)d_in[7];
    const float* mb2 = (const float*)d_in[8];
    float* ws  = (float*)d_ws;
    float* out = (float*)d_out;

    k_init <<<dim3(49),      dim3(256), 0, stream>>>(ws);
    k_big  <<<dim3(640),     dim3(256), 0, stream>>>(x, w1r, w1i, w2r, w2i, ws); // dftw(DMA) ∪ trans
    k_dfth <<<dim3(16,16),   dim3(256), 0, stream>>>(ws);
    k_mix  <<<dim3(512),     dim3(256), 0, stream>>>(ws);
    k_tail <<<dim3(336),     dim3(256), 0, stream>>>(mw1, mw2, ws);  // idfth+pstats ∪ wmlp
    k_mlp  <<<dim3(128,16),  dim3(256), 0, stream>>>(mb1, mb2, out, ws);
}